// Round 2
// baseline (391.499 us; speedup 1.0000x reference)
//
#include <hip/hip_runtime.h>

// Problem constants (from reference): N=16, H=512, W=512, K=1, F=9976, D=12
#define PN 16
#define PH 512
#define PW 512
#define PF 9976
#define PD 12

// One thread per pixel. Consecutive threads -> consecutive w, so:
//  - pix_to_face load: coalesced dword
//  - bary loads: 12B/thread contiguous (scalar, fine)
//  - attribute gather: 9 x float4 from random face (144B contiguous, 16B aligned)
//  - output: 13 coalesced dword stores, one per channel plane
__global__ __launch_bounds__(256) void interp_face_attrs_kernel(
    const int*   __restrict__ pix_to_face,   // [N*H*W]  (K=1)
    const float* __restrict__ bary,          // [N*H*W*3]
    const float* __restrict__ attr,          // [N*F*3*D] = [N*F][3][12]
    float*       __restrict__ out)           // [N][D+1][H][W]
{
    const int HW    = PH * PW;
    const int total = PN * HW;
    int tid = blockIdx.x * blockDim.x + threadIdx.x;
    if (tid >= total) return;

    const int n  = tid / HW;
    const int hw = tid - n * HW;

    const int p = pix_to_face[tid];

    const float b0 = bary[3 * tid + 0];
    const float b1 = bary[3 * tid + 1];
    const float b2 = bary[3 * tid + 2];

    float vals[PD];
    float vis;

    if (p < 0) {
        #pragma unroll
        for (int d = 0; d < PD; ++d) vals[d] = 0.0f;
        vis = 0.0f;
    } else {
        // 36 contiguous floats = 9 float4 (offset p*144B, 16B aligned)
        const float4* a4 = reinterpret_cast<const float4*>(attr + (size_t)p * (3 * PD));
        float a[36];
        #pragma unroll
        for (int i = 0; i < 9; ++i) {
            float4 v = a4[i];
            a[4 * i + 0] = v.x;
            a[4 * i + 1] = v.y;
            a[4 * i + 2] = v.z;
            a[4 * i + 3] = v.w;
        }
        #pragma unroll
        for (int d = 0; d < PD; ++d) {
            vals[d] = b0 * a[d] + b1 * a[PD + d] + b2 * a[2 * PD + d];
        }
        vis = 1.0f;
    }

    float* o = out + (size_t)n * (PD + 1) * HW + hw;
    #pragma unroll
    for (int d = 0; d < PD; ++d) {
        o[(size_t)d * HW] = vals[d];
    }
    o[(size_t)PD * HW] = vis;
}

extern "C" void kernel_launch(void* const* d_in, const int* in_sizes, int n_in,
                              void* d_out, int out_size, void* d_ws, size_t ws_size,
                              hipStream_t stream) {
    const int*   pix_to_face = (const int*)d_in[0];    // [N,H,W,1] int32
    const float* bary        = (const float*)d_in[1];  // [N,H,W,1,3] f32
    const float* attr        = (const float*)d_in[2];  // [N,F,3,D] f32
    float*       out         = (float*)d_out;          // [N,D+1,H,W] f32

    const int total  = PN * PH * PW;
    const int block  = 256;
    const int grid   = (total + block - 1) / block;

    interp_face_attrs_kernel<<<grid, block, 0, stream>>>(pix_to_face, bary, attr, out);
}